// Round 16
// baseline (116.164 us; speedup 1.0000x reference)
//
#include <hip/hip_runtime.h>
#include <stdint.h>

#define VOCAB 21128
#define NUMC  53
#define EMB   128
#define SEQ   512
#define BATCH 512

typedef __bf16 bf16x8 __attribute__((ext_vector_type(8)));
typedef float f32x4 __attribute__((ext_vector_type(4)));

__device__ __forceinline__ unsigned int f2bf1(float f) {
    union { float f; unsigned int u; } v; v.f = f;
    return (v.u + 0x7FFFu + ((v.u >> 16) & 1u)) >> 16;
}
__device__ __forceinline__ unsigned int pack2(float a, float b) {
    return f2bf1(a) | (f2bf1(b) << 16);
}

// Wp-only prep (verbatim, session-verified):
// Wp[s 0..11][g 0..7][lane 0..63][j 0..7] = w[f=g*16+(lane&15)][e=kk&127][tap=kk>>7],
// kk = s*32 + (lane>>4)*8 + j.
__global__ void prep_w(const float* __restrict__ cw, unsigned short* __restrict__ Wp) {
    int idx = blockIdx.x * blockDim.x + threadIdx.x;
    if (idx < 12 * 8 * 64 * 8) {
        int j = idx & 7, l = (idx >> 3) & 63, g = (idx >> 9) & 7, s = idx >> 12;
        int kk = s * 32 + (l >> 4) * 8 + j;
        int f = g * 16 + (l & 15);
        int tap = kk >> 7, e = kk & 127;
        Wp[idx] = (unsigned short)f2bf1(cw[(f * EMB + e) * 3 + tap]);
    }
}

// Vocabulary-factored conv table (verbatim from r15, passed at absmax 9.77e-4):
//   P[id][tap*128+f] = sum_e emb[id,e]*w[f,e,tap],  bf16, VOCAB x 384 (16.2 MB)
__launch_bounds__(256)
__global__ void pcnn_vgemm(const float* __restrict__ emb,
                           const unsigned short* __restrict__ Wp,
                           unsigned short* __restrict__ P) {
    __shared__ __align__(16) unsigned short As[64 * 128];  // 16 KB, swizzled

    const int tid  = threadIdx.x;
    const int lane = tid & 63;
    const int wn   = tid >> 6;
    const int quad = lane >> 4;
    const int lc   = lane & 15;
    const int row0 = blockIdx.x * 64;

#pragma unroll
    for (int i = 0; i < 4; ++i) {
        int task = tid + 256 * i;
        int r = task >> 4, c = task & 15;
        int gr = row0 + r;
        uint4 o = {0u, 0u, 0u, 0u};
        if (gr < VOCAB) {
            const float4* src = (const float4*)(emb + (size_t)gr * EMB + c * 8);
            float4 a = src[0], b = src[1];
            o.x = pack2(a.x, a.y); o.y = pack2(a.z, a.w);
            o.z = pack2(b.x, b.y); o.w = pack2(b.z, b.w);
        }
        *(uint4*)((char*)As + (r * 16 + (c ^ (r & 15))) * 16) = o;
    }
    __syncthreads();

    f32x4 acc[3][4][2];
#pragma unroll
    for (int t = 0; t < 3; ++t)
#pragma unroll
        for (int mt = 0; mt < 4; ++mt)
#pragma unroll
            for (int nt = 0; nt < 2; ++nt)
                acc[t][mt][nt] = (f32x4){0.f, 0.f, 0.f, 0.f};

#pragma unroll
    for (int s = 0; s < 12; ++s) {
        const int tap = s >> 2;
        const int q   = (s & 3) * 4 + quad;
        bf16x8 b0 = *(const bf16x8*)(Wp + (size_t)((s * 8 + wn * 2) * 64 + lane) * 8);
        bf16x8 b1 = *(const bf16x8*)(Wp + (size_t)((s * 8 + wn * 2 + 1) * 64 + lane) * 8);
#pragma unroll
        for (int mt = 0; mt < 4; ++mt) {
            int r = mt * 16 + lc;
            bf16x8 a = *(const bf16x8*)(As + r * 128 + (q ^ (r & 15)) * 8);
            acc[tap][mt][0] = __builtin_amdgcn_mfma_f32_16x16x32_bf16(a, b0, acc[tap][mt][0], 0, 0, 0);
            acc[tap][mt][1] = __builtin_amdgcn_mfma_f32_16x16x32_bf16(a, b1, acc[tap][mt][1], 0, 0, 0);
        }
    }

#pragma unroll
    for (int tap = 0; tap < 3; ++tap)
#pragma unroll
        for (int mt = 0; mt < 4; ++mt) {
            int grb = row0 + mt * 16 + quad * 4;
#pragma unroll
            for (int nt = 0; nt < 2; ++nt) {
                int col = tap * 128 + (wn * 2 + nt) * 16 + lc;
#pragma unroll
                for (int reg = 0; reg < 4; ++reg) {
                    int gr = grb + reg;
                    if (gr < VOCAB)
                        P[(size_t)gr * 384 + col] = (unsigned short)f2bf1(acc[tap][mt][nt][reg]);
                }
            }
        }
}

// Fused gather + pool + FC, FAT-REQUEST version (r15 post-mortem experiment):
// the ~40 µs P-gather wall is either scattered-line BYTE bandwidth (then this
// is neutral) or wave REQUEST rate (then this is ~4x). Each thread owns an
// f-quad (4 bf16 = one dwordx2 load, 8-B aligned: 768|256|fq*8 all %8==0);
// lane = ph*32 + fq, so one wave-load covers 2 positions x 128 f x 1 tap =
// 512 B = 4 lines. 768 wave-loads/block vs r15's 3072, same 201 MB total.
// 512 blocks x 1024 threads (16 waves, 2 blocks/CU, full residency).
// Masks/taps/FC identical to the r15-verified kernel; all guards valid for
// 1024 threads (r12 lesson).
__launch_bounds__(1024)
__global__ void pcnn_gather_fc(const int* __restrict__ cid, const int* __restrict__ p1,
                               const int* __restrict__ p2,
                               const unsigned short* __restrict__ P,
                               const float* __restrict__ cb,
                               const float* __restrict__ fcw,
                               const float* __restrict__ fcb,
                               float* __restrict__ out) {
    __shared__ int idsB[514];              // idsB[i] = P-row byte offset at pos i-1
    __shared__ float pstage[16][3][128];   // 24 KB: per-wave combined f-planes
    __shared__ float pooled[384];
    __shared__ float fcred[NUMC][4];

    const int b   = blockIdx.x;
    const int tid = threadIdx.x;

    const int* crow = cid + (size_t)b * SEQ;
    for (int i = tid; i < 514; i += 1024) {
        int p = i - 1;
        unsigned int id = (p >= 0 && p < SEQ) ? (unsigned int)crow[p] : 0u;
        idsB[i] = (int)(id * 768u);        // 384 cols x 2 B
    }

    int e1 = min(p1[b], p2[b]);
    int e2 = max(p1[b], p2[b]);
    if (e1 == e2) e2 = min(e1 + 1, SEQ);
    const int e1m = max(e1, 1);

    __syncthreads();

    const int lane = tid & 63;
    const int w    = tid >> 6;             // wave 0..15
    const int fq   = lane & 31;            // f-quad: f = fq*4 .. fq*4+3
    const int ph   = lane >> 5;            // position parity within the wave
    const char* Pb = (const char*)P;
    const int fo   = fq * 8;               // byte offset of the f-quad within a tap

    float smax[3][4];
#pragma unroll
    for (int s3 = 0; s3 < 3; ++s3)
#pragma unroll
        for (int j = 0; j < 4; ++j) smax[s3][j] = -1e30f;

#pragma unroll 4
    for (int pass = 0; pass < 16; ++pass) {
        int p = pass * 32 + w * 2 + ph;    // position 0..511, each exactly once
        uint2 u0 = *(const uint2*)(Pb + idsB[p]     + fo);         // tap0 @ id(p-1)
        uint2 u1 = *(const uint2*)(Pb + idsB[p + 1] + 256 + fo);   // tap1 @ id(p)
        uint2 u2 = *(const uint2*)(Pb + idsB[p + 2] + 512 + fo);   // tap2 @ id(p+1)

        // Unpack 4 bf16 lanes per tap: low ushort -> <<16, high -> mask.
        float v[4];
        {
            union { unsigned int i; float f; } c;
            float t0, t1, t2;
            c.i = u0.x << 16;         t0 = c.f;
            c.i = u1.x << 16;         t1 = c.f;
            c.i = u2.x << 16;         t2 = c.f;
            v[0] = t0 + t1 + t2;
            c.i = u0.x & 0xFFFF0000u; t0 = c.f;
            c.i = u1.x & 0xFFFF0000u; t1 = c.f;
            c.i = u2.x & 0xFFFF0000u; t2 = c.f;
            v[1] = t0 + t1 + t2;
            c.i = u0.y << 16;         t0 = c.f;
            c.i = u1.y << 16;         t1 = c.f;
            c.i = u2.y << 16;         t2 = c.f;
            v[2] = t0 + t1 + t2;
            c.i = u0.y & 0xFFFF0000u; t0 = c.f;
            c.i = u1.y & 0xFFFF0000u; t1 = c.f;
            c.i = u2.y & 0xFFFF0000u; t2 = c.f;
            v[3] = t0 + t1 + t2;
        }

        float a0 = (p < e1m)           ? 0.f : -2e30f;
        float a1 = (p >= e1 && p < e2) ? 0.f : -2e30f;
        float a2 = (p >= e2)           ? 0.f : -2e30f;
#pragma unroll
        for (int j = 0; j < 4; ++j) {
            smax[0][j] = fmaxf(smax[0][j], v[j] + a0);
            smax[1][j] = fmaxf(smax[1][j], v[j] + a1);
            smax[2][j] = fmaxf(smax[2][j], v[j] + a2);
        }
    }

    // Combine the wave's two position-streams (lane ^ 32: same fq, other ph),
    // then lanes 0-31 export this wave's f-plane.
#pragma unroll
    for (int s3 = 0; s3 < 3; ++s3)
#pragma unroll
        for (int j = 0; j < 4; ++j)
            smax[s3][j] = fmaxf(smax[s3][j], __shfl_xor(smax[s3][j], 32));
    if (ph == 0) {
#pragma unroll
        for (int s3 = 0; s3 < 3; ++s3) {
            float4 o = {smax[s3][0], smax[s3][1], smax[s3][2], smax[s3][3]};
            *(float4*)&pstage[w][s3][fq * 4] = o;
        }
    }
    __syncthreads();

    // Reduce 16 wave-planes -> pooled[384] with bias+ReLU.
    if (tid < 384) {
        int s3 = tid >> 7, ff = tid & 127;
        float m = pstage[0][s3][ff];
#pragma unroll
        for (int h = 1; h < 16; ++h) m = fmaxf(m, pstage[h][s3][ff]);
        pooled[tid] = fmaxf(m + cb[ff], 0.f);
    }
    __syncthreads();

    // FC 384 -> 53 (verbatim verified combine; summation order preserved).
    if (tid < 212) {
        int c = tid >> 2, q = tid & 3;
        const float* wrow = fcw + (size_t)c * 384 + q * 96;
        const float* pp   = pooled + q * 96;
        float sum = 0.f;
#pragma unroll 8
        for (int i = 0; i < 96; ++i) sum += wrow[i] * pp[i];
        fcred[c][q] = sum;
    }
    __syncthreads();
    if (tid < NUMC)
        out[(size_t)b * NUMC + tid] =
            fcred[tid][0] + fcred[tid][1] + fcred[tid][2] + fcred[tid][3] + fcb[tid];
}

extern "C" void kernel_launch(void* const* d_in, const int* in_sizes, int n_in,
                              void* d_out, int out_size, void* d_ws, size_t ws_size,
                              hipStream_t stream) {
    const int*   cid = (const int*)d_in[0];
    const int*   p1  = (const int*)d_in[1];
    const int*   p2  = (const int*)d_in[2];
    const float* emb = (const float*)d_in[3];
    const float* cw  = (const float*)d_in[4];
    const float* cb  = (const float*)d_in[5];
    const float* fcw = (const float*)d_in[6];
    const float* fcb = (const float*)d_in[7];
    float* out = (float*)d_out;

    // ws: Wp bf16 [49152] (98,304 B) | P bf16 [VOCAB*384] (16,226,304 B)
    unsigned short* Wp = (unsigned short*)d_ws;
    unsigned short* P  = (unsigned short*)((char*)d_ws + 98304);

    const int gemm_blocks = (VOCAB + 63) / 64;  // 331
    prep_w<<<192, 256, 0, stream>>>(cw, Wp);
    pcnn_vgemm<<<gemm_blocks, 256, 0, stream>>>(emb, Wp, P);
    pcnn_gather_fc<<<BATCH, 1024, 0, stream>>>(cid, p1, p2, P, cb, fcw, fcb, out);
}